// Round 6
// baseline (215.478 us; speedup 1.0000x reference)
//
#include <hip/hip_runtime.h>

// B=16, Q=64, K=1024, H=256, Dv=256
#define LOG2E 1.4426950408889634f
#define TANH_SCALE 2.8853900817779268f   // 2*log2(e)
#define NEG_BIG -1e30f

typedef __attribute__((ext_vector_type(8))) short bf16x8;
typedef __attribute__((ext_vector_type(4))) float f32x4;
typedef _Float16 half4 __attribute__((ext_vector_type(4)));

static __device__ __forceinline__ short f2bf(float f) {
    unsigned u = __builtin_bit_cast(unsigned, f);
    u += 0x7fffu + ((u >> 16) & 1u);     // round-to-nearest-even
    return (short)(u >> 16);
}

// ---------------------------------------------------------------------------
// Projection via bf16 MFMA, no LDS: direct-from-global fragments.
// e_all rows 0..1023 = exp2(TS * queries@Wq^T), rows 1024..17407 = keys@Wk^T.
// Block = 32M x 128N (4 waves, wave = 16M x 64N), grid 1088 blocks.
// ---------------------------------------------------------------------------
__global__ __launch_bounds__(256) void proj_mfma(const float* __restrict__ queries,
                                                 const float* __restrict__ keys,
                                                 const float* __restrict__ Wq,
                                                 const float* __restrict__ Wk,
                                                 float* __restrict__ e_all) {
    const int mt = blockIdx.x >> 1, nt = blockIdx.x & 1;
    const int tid = threadIdx.x;
    const int w = tid >> 6, lane = tid & 63;
    const int wm = w >> 1, wn = w & 1;
    const int r = lane & 15, kq = lane >> 4;
    const int m0 = mt << 5;
    const int ncol = (nt << 7) + (wn << 6);

    const float* A; const float* W; int ar;
    if (m0 < 1024) { A = queries; W = Wq; ar = m0; }
    else           { A = keys;    W = Wk; ar = m0 - 1024; }

    const float* aptr = &A[(size_t)(ar + (wm << 4) + r) * 256];
    f32x4 acc[4] = {};

    #pragma unroll 2
    for (int ks = 0; ks < 8; ++ks) {
        const int k0 = (ks << 5) + (kq << 3);
        float4 fa0 = *reinterpret_cast<const float4*>(aptr + k0);
        float4 fa1 = *reinterpret_cast<const float4*>(aptr + k0 + 4);
        bf16x8 a = {f2bf(fa0.x), f2bf(fa0.y), f2bf(fa0.z), f2bf(fa0.w),
                    f2bf(fa1.x), f2bf(fa1.y), f2bf(fa1.z), f2bf(fa1.w)};
        #pragma unroll
        for (int nj = 0; nj < 4; ++nj) {
            const float* bp = &W[(size_t)(ncol + (nj << 4) + r) * 256 + k0];
            float4 fb0 = *reinterpret_cast<const float4*>(bp);
            float4 fb1 = *reinterpret_cast<const float4*>(bp + 4);
            bf16x8 bb = {f2bf(fb0.x), f2bf(fb0.y), f2bf(fb0.z), f2bf(fb0.w),
                         f2bf(fb1.x), f2bf(fb1.y), f2bf(fb1.z), f2bf(fb1.w)};
            acc[nj] = __builtin_amdgcn_mfma_f32_16x16x32_bf16(a, bb, acc[nj], 0, 0, 0);
        }
    }
    // C/D: col = lane&15 (r), row = kq*4 + t
    #pragma unroll
    for (int nj = 0; nj < 4; ++nj)
        #pragma unroll
        for (int t = 0; t < 4; ++t) {
            int row = m0 + (wm << 4) + (kq << 2) + t;
            e_all[(size_t)row * 256 + ncol + (nj << 4) + r] =
                __builtin_amdgcn_exp2f(TANH_SCALE * acc[nj][t]);
        }
}

// ---------------------------------------------------------------------------
// Split-K fused attention with register-prefetch pipeline (T14).
// Grid (qt:8, b:16, seg:8); 4 waves, 2 q/wave, seg = 128 keys = 2 chunks of 64,
// each chunk in two 128-h halves. ek half staged global->reg->LDS; next half's
// loads issued before compute so HBM latency hides under the rcp loop.
// q halves in q_lds (256 entries, tid 1:1); wv staged ONCE in wv_lds (fix for
// the round-5 bug: 288-item staging with 256 threads left wv unwritten).
// ---------------------------------------------------------------------------
#define ATTN_ISSUE(RS, RQ, STG) do {                                           \
    const float4* src_ = ekb + (((STG) >> 1) << 12) + (((STG) & 1) << 5);      \
    _Pragma("unroll")                                                          \
    for (int i_ = 0; i_ < 8; ++i_) {                                           \
        int d_ = (i_ << 8) + tid;                                              \
        RS[i_] = src_[(d_ >> 5) * 64 + (d_ & 31)];                             \
    }                                                                          \
    RQ = eqf[(size_t)((b << 6) + q0 + (tid >> 5)) * 64                         \
             + (((STG) & 1) << 5) + (tid & 31)];                               \
} while (0)

#define ATTN_WRITE(RS, RQ) do {                                                \
    _Pragma("unroll")                                                          \
    for (int i_ = 0; i_ < 8; ++i_) {                                           \
        int d_ = (i_ << 8) + tid;                                              \
        int row_ = d_ >> 5, col_ = d_ & 31;                                    \
        ek_lds[(row_ << 5) + (col_ ^ (row_ & 7))] = RS[i_];                    \
    }                                                                          \
    q_lds[tid] = RQ;                                                           \
} while (0)

#define ATTN_COMPUTE(S0, S1, HOFF) do {                                        \
    _Pragma("unroll 8")                                                        \
    for (int jh = 0; jh < 32; ++jh) {                                          \
        float4 kv = ek_lds[krow + (jh ^ ksw)];                                 \
        float4 qa = q_lds[qoff + jh];                                          \
        float4 qb = q_lds[qoff + 32 + jh];                                     \
        float4 wc = wv_lds[(HOFF) + jh];                                       \
        S0 += wc.x * __builtin_amdgcn_rcpf(fmaf(kv.x, qa.x, 1.0f));            \
        S0 += wc.y * __builtin_amdgcn_rcpf(fmaf(kv.y, qa.y, 1.0f));            \
        S0 += wc.z * __builtin_amdgcn_rcpf(fmaf(kv.z, qa.z, 1.0f));            \
        S0 += wc.w * __builtin_amdgcn_rcpf(fmaf(kv.w, qa.w, 1.0f));            \
        S1 += wc.x * __builtin_amdgcn_rcpf(fmaf(kv.x, qb.x, 1.0f));            \
        S1 += wc.y * __builtin_amdgcn_rcpf(fmaf(kv.y, qb.y, 1.0f));            \
        S1 += wc.z * __builtin_amdgcn_rcpf(fmaf(kv.z, qb.z, 1.0f));            \
        S1 += wc.w * __builtin_amdgcn_rcpf(fmaf(kv.w, qb.w, 1.0f));            \
    }                                                                          \
} while (0)

__global__ __launch_bounds__(256, 4) void attn_kernel(const float* __restrict__ e_all,
                                                      const float* __restrict__ values,
                                                      const int* __restrict__ valid_lens,
                                                      const float* __restrict__ wv,
                                                      _Float16* __restrict__ part_acc,
                                                      float* __restrict__ part_m,
                                                      float* __restrict__ part_l) {
    __shared__ float4 ek_lds[64 * 32];    // 32 KB: 64 keys x 128 h (one half), swizzled
    __shared__ float4 q_lds[256];         // 8 q-rows, current h-half: 4 KB
    __shared__ float4 wv_lds[64];         // full wv (both halves): 1 KB, staged once
    __shared__ float  p_lds[8][64];       // 2 KB

    const int tid = threadIdx.x;
    const int w = tid >> 6, lane = tid & 63;
    const int qt = blockIdx.x, b = blockIdx.y, seg = blockIdx.z;
    const int q0 = qt << 3;
    const int vl = valid_lens[b];
    const int kstart = seg << 7;
    const int pA = (((b << 6) + q0 + (w << 1)) << 3) + seg;
    const int pB = pA + 8;

    if (kstart >= vl) {                   // inactive segment: neutral partials
        half4 z = {};
        *reinterpret_cast<half4*>(&part_acc[(size_t)pA * 256 + (lane << 2)]) = z;
        *reinterpret_cast<half4*>(&part_acc[(size_t)pB * 256 + (lane << 2)]) = z;
        if (lane == 0) {
            part_m[pA] = NEG_BIG; part_l[pA] = 0.f;
            part_m[pB] = NEG_BIG; part_l[pB] = 0.f;
        }
        return;
    }

    const int kend = min(kstart + 128, vl);
    const int nchunks = (kend - kstart + 63) >> 6;
    const int nst = nchunks << 1;

    const float4* ekb = reinterpret_cast<const float4*>(&e_all[(size_t)(1024 + b * 1024 + kstart) * 256]);
    const float4* eqf = reinterpret_cast<const float4*>(e_all);
    const float4* wvf = reinterpret_cast<const float4*>(wv);

    if (tid < 64) wv_lds[tid] = wvf[tid];   // visible after first loop barrier

    const int krow = lane << 5;
    const int ksw  = lane & 7;
    const int qoff = w << 6;              // (w*2)*32

    float mA = -INFINITY, lA = 0.f, mB = -INFINITY, lB = 0.f;
    f32x4 accA = {0.f, 0.f, 0.f, 0.f}, accB = {0.f, 0.f, 0.f, 0.f};

    float4 rsA[8], rsB[8];
    float4 rqA, rqB;

    ATTN_ISSUE(rsA, rqA, 0);

    for (int c = 0; c < nchunks; ++c) {
        const int ck = kstart + (c << 6);
        float s0 = 0.f, s1 = 0.f;

        // ---- half 0 (h 0..127) ----
        __syncthreads();                  // prior consumers of LDS done (+ wv_lds visible)
        ATTN_WRITE(rsA, rqA);
        __syncthreads();
        ATTN_ISSUE(rsB, rqB, (c << 1) + 1);   // always < nst
        ATTN_COMPUTE(s0, s1, 0);

        // ---- half 1 (h 128..255) ----
        __syncthreads();
        ATTN_WRITE(rsB, rqB);
        __syncthreads();
        if ((c << 1) + 2 < nst) ATTN_ISSUE(rsA, rqA, (c << 1) + 2);
        ATTN_COMPUTE(s0, s1, 32);

        // ---- mask + online softmax ----
        float sA_ = -2.0f * s0, sB_ = -2.0f * s1;
        if (ck + lane >= vl) { sA_ = NEG_BIG; sB_ = NEG_BIG; }
        float mcA = sA_, mcB = sB_;
        #pragma unroll
        for (int o = 32; o > 0; o >>= 1) {
            mcA = fmaxf(mcA, __shfl_xor(mcA, o));
            mcB = fmaxf(mcB, __shfl_xor(mcB, o));
        }
        float mnA = fmaxf(mA, mcA), mnB = fmaxf(mB, mcB);
        float rA = __builtin_amdgcn_exp2f((mA - mnA) * LOG2E);
        float rB = __builtin_amdgcn_exp2f((mB - mnB) * LOG2E);
        float pA_ = __builtin_amdgcn_exp2f((sA_ - mnA) * LOG2E);
        float pB_ = __builtin_amdgcn_exp2f((sB_ - mnB) * LOG2E);
        float lcA = pA_, lcB = pB_;
        #pragma unroll
        for (int o = 32; o > 0; o >>= 1) {
            lcA += __shfl_xor(lcA, o);
            lcB += __shfl_xor(lcB, o);
        }
        lA = lA * rA + lcA; mA = mnA;
        lB = lB * rB + lcB; mB = mnB;
        accA *= rA; accB *= rB;
        p_lds[(w << 1) + 0][lane] = pA_;  // same-wave produce/consume
        p_lds[(w << 1) + 1][lane] = pB_;

        // ---- PV ----
        const int nv = min(64, kend - ck);
        const float* vsrc = &values[(size_t)(b * 1024 + ck) * 256 + (lane << 2)];
        if (nv == 64) {
            #pragma unroll 4
            for (int j4 = 0; j4 < 16; ++j4) {
                float4 pa4 = *reinterpret_cast<const float4*>(&p_lds[(w << 1)][j4 << 2]);
                float4 pb4 = *reinterpret_cast<const float4*>(&p_lds[(w << 1) + 1][j4 << 2]);
                #pragma unroll
                for (int jj = 0; jj < 4; ++jj) {
                    float pa = ((const float*)&pa4)[jj], pb = ((const float*)&pb4)[jj];
                    float4 v = *reinterpret_cast<const float4*>(vsrc + (((j4 << 2) + jj)) * 256);
                    accA.x += pa * v.x; accA.y += pa * v.y; accA.z += pa * v.z; accA.w += pa * v.w;
                    accB.x += pb * v.x; accB.y += pb * v.y; accB.z += pb * v.z; accB.w += pb * v.w;
                }
            }
        } else {
            for (int j = 0; j < nv; ++j) {
                float pa = p_lds[(w << 1)][j], pb = p_lds[(w << 1) + 1][j];
                float4 v = *reinterpret_cast<const float4*>(vsrc + j * 256);
                accA.x += pa * v.x; accA.y += pa * v.y; accA.z += pa * v.z; accA.w += pa * v.w;
                accB.x += pb * v.x; accB.y += pb * v.y; accB.z += pb * v.z; accB.w += pb * v.w;
            }
        }
    }

    if (lane == 0) {
        part_m[pA] = mA; part_l[pA] = lA;
        part_m[pB] = mB; part_l[pB] = lB;
    }
    half4 ha = {(_Float16)accA.x, (_Float16)accA.y, (_Float16)accA.z, (_Float16)accA.w};
    half4 hb = {(_Float16)accB.x, (_Float16)accB.y, (_Float16)accB.z, (_Float16)accB.w};
    *reinterpret_cast<half4*>(&part_acc[(size_t)pA * 256 + (lane << 2)]) = ha;
    *reinterpret_cast<half4*>(&part_acc[(size_t)pB * 256 + (lane << 2)]) = hb;
}

// ---------------------------------------------------------------------------
// Combine 8 split-K partials per (b,q).
// ---------------------------------------------------------------------------
__global__ __launch_bounds__(256) void combine_kernel(const _Float16* __restrict__ part_acc,
                                                      const float* __restrict__ part_m,
                                                      const float* __restrict__ part_l,
                                                      float* __restrict__ out) {
    const int tid = threadIdx.x;
    const int w = tid >> 6, lane = tid & 63;
    const int b = blockIdx.x >> 4, qt = blockIdx.x & 15;
    const int q = (qt << 2) + w;
    const int base = ((b << 6) + q) << 3;

    float mm[8], ll[8];
    #pragma unroll
    for (int i = 0; i < 8; ++i) { mm[i] = part_m[base + i]; ll[i] = part_l[base + i]; }
    float M = mm[0];
    #pragma unroll
    for (int i = 1; i < 8; ++i) M = fmaxf(M, mm[i]);
    float wt[8];
    float L = 0.f;
    #pragma unroll
    for (int i = 0; i < 8; ++i) {
        wt[i] = __builtin_amdgcn_exp2f((mm[i] - M) * LOG2E);
        L += wt[i] * ll[i];
    }
    float invL = 1.0f / L;
    float4 o = {0.f, 0.f, 0.f, 0.f};
    #pragma unroll
    for (int i = 0; i < 8; ++i) {
        half4 v = *reinterpret_cast<const half4*>(&part_acc[(size_t)(base + i) * 256 + (lane << 2)]);
        o.x += wt[i] * (float)v.x; o.y += wt[i] * (float)v.y;
        o.z += wt[i] * (float)v.z; o.w += wt[i] * (float)v.w;
    }
    o.x *= invL; o.y *= invL; o.z *= invL; o.w *= invL;
    *reinterpret_cast<float4*>(&out[(size_t)((b << 6) + q) * 256 + (lane << 2)]) = o;
}

extern "C" void kernel_launch(void* const* d_in, const int* in_sizes, int n_in,
                              void* d_out, int out_size, void* d_ws, size_t ws_size,
                              hipStream_t stream) {
    const float* queries    = (const float*)d_in[0];  // [16,64,256]
    const float* keys       = (const float*)d_in[1];  // [16,1024,256]
    const float* values     = (const float*)d_in[2];  // [16,1024,256]
    const int*   valid_lens = (const int*)d_in[3];    // [16]
    const float* Wq         = (const float*)d_in[4];  // [256,256]
    const float* Wk         = (const float*)d_in[5];  // [256,256]
    const float* wv         = (const float*)d_in[6];  // [256]
    float* out = (float*)d_out;                       // [16,64,256]

    float*     e_all    = (float*)d_ws;                       // 17408*256 f32 (17.8 MB)
    _Float16*  part_acc = (_Float16*)(e_all + 4456448);       // 16*64*8*256 fp16 (4.2 MB)
    float*     part_m   = (float*)(part_acc + 2097152);       // 8192
    float*     part_l   = part_m + 8192;                      // 8192

    // E = exp2(TANH_SCALE * proj): rows 0..1023 queries, 1024.. keys
    proj_mfma<<<dim3(1088), 256, 0, stream>>>(queries, keys, Wq, Wk, e_all);
    // split-K fused scores + masked online softmax + PV partials
    attn_kernel<<<dim3(8, 16, 8), 256, 0, stream>>>(e_all, values, valid_lens, wv,
                                                    part_acc, part_m, part_l);
    // merge partials
    combine_kernel<<<dim3(256), 256, 0, stream>>>(part_acc, part_m, part_l, out);
}

// Round 7
// 193.404 us; speedup vs baseline: 1.1141x; 1.1141x over previous
//
#include <hip/hip_runtime.h>

// B=16, Q=64, K=1024, H=256, Dv=256
#define LOG2E 1.4426950408889634f
#define TANH_SCALE 2.8853900817779268f   // 2*log2(e)
#define NEG_BIG -1e30f

typedef __attribute__((ext_vector_type(8))) short bf16x8;
typedef __attribute__((ext_vector_type(4))) float f32x4;
typedef _Float16 half4 __attribute__((ext_vector_type(4)));

static __device__ __forceinline__ short f2bf(float f) {
    unsigned u = __builtin_bit_cast(unsigned, f);
    u += 0x7fffu + ((u >> 16) & 1u);     // round-to-nearest-even
    return (short)(u >> 16);
}

// ---------------------------------------------------------------------------
// Projection via bf16 MFMA, no LDS: direct-from-global fragments.
// queries -> eq[row][h]  (row-major, 1024x256)
// keys    -> ek4[h>>2][global_key].{h&3}  (h-grouped transpose, float4 per
//            (h-group, key)) so the attn score loop reads ek coalesced.
// Block = 32M x 128N (4 waves, wave = 16M x 64N), grid 1088 blocks.
// ---------------------------------------------------------------------------
__global__ __launch_bounds__(256) void proj_mfma(const float* __restrict__ queries,
                                                 const float* __restrict__ keys,
                                                 const float* __restrict__ Wq,
                                                 const float* __restrict__ Wk,
                                                 float* __restrict__ eq,
                                                 float* __restrict__ ek4) {
    const int mt = blockIdx.x >> 1, nt = blockIdx.x & 1;
    const int tid = threadIdx.x;
    const int w = tid >> 6, lane = tid & 63;
    const int wm = w >> 1, wn = w & 1;
    const int r = lane & 15, kq = lane >> 4;
    const int m0 = mt << 5;
    const int ncol = (nt << 7) + (wn << 6);

    const float* A; const float* W; int ar;
    if (m0 < 1024) { A = queries; W = Wq; ar = m0; }
    else           { A = keys;    W = Wk; ar = m0 - 1024; }

    const float* aptr = &A[(size_t)(ar + (wm << 4) + r) * 256];
    f32x4 acc[4] = {};

    #pragma unroll 2
    for (int ks = 0; ks < 8; ++ks) {
        const int k0 = (ks << 5) + (kq << 3);
        float4 fa0 = *reinterpret_cast<const float4*>(aptr + k0);
        float4 fa1 = *reinterpret_cast<const float4*>(aptr + k0 + 4);
        bf16x8 a = {f2bf(fa0.x), f2bf(fa0.y), f2bf(fa0.z), f2bf(fa0.w),
                    f2bf(fa1.x), f2bf(fa1.y), f2bf(fa1.z), f2bf(fa1.w)};
        #pragma unroll
        for (int nj = 0; nj < 4; ++nj) {
            const float* bp = &W[(size_t)(ncol + (nj << 4) + r) * 256 + k0];
            float4 fb0 = *reinterpret_cast<const float4*>(bp);
            float4 fb1 = *reinterpret_cast<const float4*>(bp + 4);
            bf16x8 bb = {f2bf(fb0.x), f2bf(fb0.y), f2bf(fb0.z), f2bf(fb0.w),
                         f2bf(fb1.x), f2bf(fb1.y), f2bf(fb1.z), f2bf(fb1.w)};
            acc[nj] = __builtin_amdgcn_mfma_f32_16x16x32_bf16(a, bb, acc[nj], 0, 0, 0);
        }
    }
    // C/D: col = lane&15 (r), row = kq*4 + t
    if (m0 < 1024) {
        #pragma unroll
        for (int nj = 0; nj < 4; ++nj)
            #pragma unroll
            for (int t = 0; t < 4; ++t) {
                int row = m0 + (wm << 4) + (kq << 2) + t;
                int col = ncol + (nj << 4) + r;
                eq[(size_t)row * 256 + col] =
                    __builtin_amdgcn_exp2f(TANH_SCALE * acc[nj][t]);
            }
    } else {
        #pragma unroll
        for (int nj = 0; nj < 4; ++nj)
            #pragma unroll
            for (int t = 0; t < 4; ++t) {
                int R   = (m0 - 1024) + (wm << 4) + (kq << 2) + t;   // global key
                int col = ncol + (nj << 4) + r;                       // h
                size_t idx = ((size_t)((col >> 2) << 14) + R) * 4 + (col & 3);
                ek4[idx] = __builtin_amdgcn_exp2f(TANH_SCALE * acc[nj][t]);
            }
    }
}

// ---------------------------------------------------------------------------
// Split-K fused attention, NO ek staging (ek is L2/L3-fit; lesson: don't stage
// cache-fit data). ek4 read directly from global, coalesced float4 per h-group.
// 1D grid 1024 blocks, XCD-bijective swizzle so the 8 qt-sibling blocks
// (same (b,seg), sharing ek+V reads) land on one XCD's L2.
// 4 waves, 2 q/wave; q rows + wv in LDS (broadcast reads); fp16 partials.
// ---------------------------------------------------------------------------
__global__ __launch_bounds__(256, 4) void attn_kernel(const float* __restrict__ eq,
                                                      const float* __restrict__ ek4,
                                                      const float* __restrict__ values,
                                                      const int* __restrict__ valid_lens,
                                                      const float* __restrict__ wv,
                                                      _Float16* __restrict__ part_acc,
                                                      float* __restrict__ part_m,
                                                      float* __restrict__ part_l) {
    __shared__ float4 q_lds[8 * 64];     // 8 q rows x 256 h: 8 KB
    __shared__ float4 wv_lds[64];        // 1 KB
    __shared__ float  p_lds[8][64];      // 2 KB

    const int tid = threadIdx.x;
    const int w = tid >> 6, lane = tid & 63;

    // XCD-bijective decode: blocks u with u&7 == x land on XCD x; give each
    // XCD 16 (b,seg) pairs, all 8 qt-siblings of a pair contiguous in u>>3.
    const unsigned u = blockIdx.x;       // 0..1023
    const int xcd = u & 7;
    const int j   = u >> 3;              // 0..127
    const int qt  = j & 7;
    const int pair = ((j >> 3) << 3) | xcd;   // 0..127
    const int b = pair & 15, seg = pair >> 4;

    const int q0 = qt << 3;
    const int vl = valid_lens[b];
    const int kstart = seg << 7;
    const int pA = (((b << 6) + q0 + (w << 1)) << 3) + seg;
    const int pB = pA + 8;

    if (kstart >= vl) {                   // inactive segment: neutral partials
        half4 z = {};
        *reinterpret_cast<half4*>(&part_acc[(size_t)pA * 256 + (lane << 2)]) = z;
        *reinterpret_cast<half4*>(&part_acc[(size_t)pB * 256 + (lane << 2)]) = z;
        if (lane == 0) {
            part_m[pA] = NEG_BIG; part_l[pA] = 0.f;
            part_m[pB] = NEG_BIG; part_l[pB] = 0.f;
        }
        return;
    }

    // stage q rows (q0..q0+7, full 256 h) + wv once
    const float4* eqf = reinterpret_cast<const float4*>(eq);
    #pragma unroll
    for (int it = 0; it < 2; ++it) {
        int idx = tid + (it << 8);        // 0..511
        q_lds[idx] = eqf[(size_t)((b << 6) + q0 + (idx >> 6)) * 64 + (idx & 63)];
    }
    if (tid < 64) wv_lds[tid] = *(reinterpret_cast<const float4*>(wv) + tid);
    __syncthreads();

    const int kend = min(kstart + 128, vl);
    const int nchunks = (kend - kstart + 63) >> 6;

    const float4* ek4f = reinterpret_cast<const float4*>(ek4);
    const float4* qa4 = &q_lds[(w << 1) << 6];
    const float4* qb4 = qa4 + 64;

    float mA = -INFINITY, lA = 0.f, mB = -INFINITY, lB = 0.f;
    f32x4 accA = {0.f, 0.f, 0.f, 0.f}, accB = {0.f, 0.f, 0.f, 0.f};

    for (int c = 0; c < nchunks; ++c) {
        const int ck = kstart + (c << 6);
        const float4* ekc = ek4f + (size_t)((b << 10) + ck + lane);

        float sa0 = 0.f, sa1 = 0.f, sa2 = 0.f, sa3 = 0.f;
        float sb0 = 0.f, sb1 = 0.f, sb2 = 0.f, sb3 = 0.f;
        #pragma unroll 8
        for (int h4 = 0; h4 < 64; ++h4) {
            float4 ev = ekc[h4 << 14];            // coalesced: lane-consecutive f4
            float4 qa = qa4[h4];                   // LDS broadcast
            float4 qb = qb4[h4];
            float4 wc = wv_lds[h4];
            sa0 += wc.x * __builtin_amdgcn_rcpf(fmaf(ev.x, qa.x, 1.0f));
            sa1 += wc.y * __builtin_amdgcn_rcpf(fmaf(ev.y, qa.y, 1.0f));
            sa2 += wc.z * __builtin_amdgcn_rcpf(fmaf(ev.z, qa.z, 1.0f));
            sa3 += wc.w * __builtin_amdgcn_rcpf(fmaf(ev.w, qa.w, 1.0f));
            sb0 += wc.x * __builtin_amdgcn_rcpf(fmaf(ev.x, qb.x, 1.0f));
            sb1 += wc.y * __builtin_amdgcn_rcpf(fmaf(ev.y, qb.y, 1.0f));
            sb2 += wc.z * __builtin_amdgcn_rcpf(fmaf(ev.z, qb.z, 1.0f));
            sb3 += wc.w * __builtin_amdgcn_rcpf(fmaf(ev.w, qb.w, 1.0f));
        }
        float sA_ = -2.0f * ((sa0 + sa1) + (sa2 + sa3));
        float sB_ = -2.0f * ((sb0 + sb1) + (sb2 + sb3));
        if (ck + lane >= vl) { sA_ = NEG_BIG; sB_ = NEG_BIG; }

        // ---- online softmax (per wave, per q) ----
        float mcA = sA_, mcB = sB_;
        #pragma unroll
        for (int o = 32; o > 0; o >>= 1) {
            mcA = fmaxf(mcA, __shfl_xor(mcA, o));
            mcB = fmaxf(mcB, __shfl_xor(mcB, o));
        }
        float mnA = fmaxf(mA, mcA), mnB = fmaxf(mB, mcB);
        float rA = __builtin_amdgcn_exp2f((mA - mnA) * LOG2E);
        float rB = __builtin_amdgcn_exp2f((mB - mnB) * LOG2E);
        float pA_ = __builtin_amdgcn_exp2f((sA_ - mnA) * LOG2E);
        float pB_ = __builtin_amdgcn_exp2f((sB_ - mnB) * LOG2E);
        float lcA = pA_, lcB = pB_;
        #pragma unroll
        for (int o = 32; o > 0; o >>= 1) {
            lcA += __shfl_xor(lcA, o);
            lcB += __shfl_xor(lcB, o);
        }
        lA = lA * rA + lcA; mA = mnA;
        lB = lB * rB + lcB; mB = mnB;
        accA *= rA; accB *= rB;
        p_lds[(w << 1) + 0][lane] = pA_;  // same-wave produce/consume
        p_lds[(w << 1) + 1][lane] = pB_;

        // ---- PV ----
        const int nv = min(64, kend - ck);
        const float* vsrc = &values[(size_t)(b * 1024 + ck) * 256 + (lane << 2)];
        if (nv == 64) {
            #pragma unroll 4
            for (int j4 = 0; j4 < 16; ++j4) {
                float4 pa4 = *reinterpret_cast<const float4*>(&p_lds[(w << 1)][j4 << 2]);
                float4 pb4 = *reinterpret_cast<const float4*>(&p_lds[(w << 1) + 1][j4 << 2]);
                #pragma unroll
                for (int jj = 0; jj < 4; ++jj) {
                    float pa = ((const float*)&pa4)[jj], pb = ((const float*)&pb4)[jj];
                    float4 v = *reinterpret_cast<const float4*>(vsrc + (((j4 << 2) + jj)) * 256);
                    accA.x += pa * v.x; accA.y += pa * v.y; accA.z += pa * v.z; accA.w += pa * v.w;
                    accB.x += pb * v.x; accB.y += pb * v.y; accB.z += pb * v.z; accB.w += pb * v.w;
                }
            }
        } else {
            for (int jx = 0; jx < nv; ++jx) {
                float pa = p_lds[(w << 1)][jx], pb = p_lds[(w << 1) + 1][jx];
                float4 v = *reinterpret_cast<const float4*>(vsrc + jx * 256);
                accA.x += pa * v.x; accA.y += pa * v.y; accA.z += pa * v.z; accA.w += pa * v.w;
                accB.x += pb * v.x; accB.y += pb * v.y; accB.z += pb * v.z; accB.w += pb * v.w;
            }
        }
    }

    if (lane == 0) {
        part_m[pA] = mA; part_l[pA] = lA;
        part_m[pB] = mB; part_l[pB] = lB;
    }
    half4 ha = {(_Float16)accA.x, (_Float16)accA.y, (_Float16)accA.z, (_Float16)accA.w};
    half4 hb = {(_Float16)accB.x, (_Float16)accB.y, (_Float16)accB.z, (_Float16)accB.w};
    *reinterpret_cast<half4*>(&part_acc[(size_t)pA * 256 + (lane << 2)]) = ha;
    *reinterpret_cast<half4*>(&part_acc[(size_t)pB * 256 + (lane << 2)]) = hb;
}

// ---------------------------------------------------------------------------
// Combine 8 split-K partials per (b,q).
// ---------------------------------------------------------------------------
__global__ __launch_bounds__(256) void combine_kernel(const _Float16* __restrict__ part_acc,
                                                      const float* __restrict__ part_m,
                                                      const float* __restrict__ part_l,
                                                      float* __restrict__ out) {
    const int tid = threadIdx.x;
    const int w = tid >> 6, lane = tid & 63;
    const int b = blockIdx.x >> 4, qt = blockIdx.x & 15;
    const int q = (qt << 2) + w;
    const int base = ((b << 6) + q) << 3;

    float mm[8], ll[8];
    #pragma unroll
    for (int i = 0; i < 8; ++i) { mm[i] = part_m[base + i]; ll[i] = part_l[base + i]; }
    float M = mm[0];
    #pragma unroll
    for (int i = 1; i < 8; ++i) M = fmaxf(M, mm[i]);
    float wt[8];
    float L = 0.f;
    #pragma unroll
    for (int i = 0; i < 8; ++i) {
        wt[i] = __builtin_amdgcn_exp2f((mm[i] - M) * LOG2E);
        L += wt[i] * ll[i];
    }
    float invL = 1.0f / L;
    float4 o = {0.f, 0.f, 0.f, 0.f};
    #pragma unroll
    for (int i = 0; i < 8; ++i) {
        half4 v = *reinterpret_cast<const half4*>(&part_acc[(size_t)(base + i) * 256 + (lane << 2)]);
        o.x += wt[i] * (float)v.x; o.y += wt[i] * (float)v.y;
        o.z += wt[i] * (float)v.z; o.w += wt[i] * (float)v.w;
    }
    o.x *= invL; o.y *= invL; o.z *= invL; o.w *= invL;
    *reinterpret_cast<float4*>(&out[(size_t)((b << 6) + q) * 256 + (lane << 2)]) = o;
}

extern "C" void kernel_launch(void* const* d_in, const int* in_sizes, int n_in,
                              void* d_out, int out_size, void* d_ws, size_t ws_size,
                              hipStream_t stream) {
    const float* queries    = (const float*)d_in[0];  // [16,64,256]
    const float* keys       = (const float*)d_in[1];  // [16,1024,256]
    const float* values     = (const float*)d_in[2];  // [16,1024,256]
    const int*   valid_lens = (const int*)d_in[3];    // [16]
    const float* Wq         = (const float*)d_in[4];  // [256,256]
    const float* Wk         = (const float*)d_in[5];  // [256,256]
    const float* wv         = (const float*)d_in[6];  // [256]
    float* out = (float*)d_out;                       // [16,64,256]

    float*     eq       = (float*)d_ws;                       // 1024*256 f32   (1 MB)
    float*     ek4      = eq + 262144;                        // 64*16384*4 f32 (16 MB)
    _Float16*  part_acc = (_Float16*)(ek4 + 4194304);         // 16*64*8*256 fp16 (4 MB)
    float*     part_m   = (float*)(part_acc + 2097152);       // 8192
    float*     part_l   = part_m + 8192;                      // 8192

    // projections: eq row-major; ek transposed+h-grouped for coalesced attn reads
    proj_mfma<<<dim3(1088), 256, 0, stream>>>(queries, keys, Wq, Wk, eq, ek4);
    // split-K fused scores + masked online softmax + PV partials (no ek staging)
    attn_kernel<<<dim3(1024), 256, 0, stream>>>(eq, ek4, values, valid_lens, wv,
                                                part_acc, part_m, part_l);
    // merge partials
    combine_kernel<<<dim3(256), 256, 0, stream>>>(part_acc, part_m, part_l, out);
}